// Round 5
// baseline (253206.885 us; speedup 1.0000x reference)
//
#include <hip/hip_runtime.h>

#define S_LEN 32768
#define EMB   256
#define HID   512
#define G3H   1536   // 3*HID
#define NBLK  128    // launched; active iff bid%8==0 (co-locate on XCD 0)
#define NTHR  512
#define NOUT  8

// ws layout (float units):
// [0, 9216)        gx_table (6 x 1536)  : emb@W_ih.T + b_ih
// [9216, 11264)    hbuf: 2 x 512 tagged u64 words. word = (tag<<32)|f32bits
#define WS_GX    0
#define WS_HBUF  9216

__global__ __launch_bounds__(256) void gru_precompute_kernel(
    const float* __restrict__ emb, const float* __restrict__ W_ih,
    const float* __restrict__ b_ih, float* __restrict__ ws)
{
    int idx = blockIdx.x * 256 + threadIdx.x;
    if (idx < 6 * G3H) {
        int v = idx / G3H, r = idx - v * G3H;
        const float* er = emb + v * EMB;
        const float* wr = W_ih + r * EMB;
        float s = 0.f;
        #pragma unroll 8
        for (int e = 0; e < EMB; ++e) s += er[e] * wr[e];
        ws[WS_GX + idx] = s + b_ih[r];
    }
}

// Persistent GRU: 16 active WGs (bid%8==0 -> all on XCD 0, sharing one L2).
// WG rank r owns h rows [r*32, r*32+32). rowg = tid>>4, k = tid&15.
// Lane k owns columns {c*64 + k*4 .. +3, c=0..7} of its row, for all 3 gates:
// 24 float4 = 96 weight VGPRs/lane, PINNED via empty asm so the allocator
// cannot rematerialize the loads inside the loop (round-4 failure mode).
// h exchange: tagged (tag<<32|value) u64 words. Producer double-stores
// (sc0 -> shared XCD L2 fast path; sc0 sc1 -> MALL safety). Consumer polls
// sc0, escalating to sc0 sc1 every 64 misses. Tag exact-match + determinism
// across graph replays make stale reads benign.
__global__ __launch_bounds__(512)
__attribute__((amdgpu_waves_per_eu(2, 2)))
void gru_persistent_kernel(
    const int* __restrict__ seq, const float* __restrict__ W_hh,
    const float* __restrict__ b_hh, const float* __restrict__ W_out,
    const float* __restrict__ b_out, float* __restrict__ ws,
    float* __restrict__ out)
{
    if (blockIdx.x & 7) return;                 // actives land on XCD 0
    const int r    = blockIdx.x >> 3;           // rank 0..15
    const int tid  = threadIdx.x;
    const int k    = tid & 15;                  // column-slice lane
    const int rowg = tid >> 4;                  // local row 0..31
    const int row  = r * 32 + rowg;             // global h row

    __shared__ __align__(16) float h_lds[2][HID];
    __shared__ float gx_lds[6 * 96];            // [v][gate][rowg], b_hh folded for r,z
    __shared__ float bhn_lds[32];
    __shared__ unsigned char seq_lds[S_LEN];

    unsigned long long* hbuf = (unsigned long long*)(ws + WS_HBUF);

    // ---- one-time weight load into registers ----
    // WR[c] = W_hh[row,       c*64 + k*4 .. +3]
    float4 WR[8], WZ[8], WN[8];
    {
        const float4* pr = (const float4*)(W_hh + (size_t)(0 * HID + row) * HID) + k;
        const float4* pz = (const float4*)(W_hh + (size_t)(1 * HID + row) * HID) + k;
        const float4* pn = (const float4*)(W_hh + (size_t)(2 * HID + row) * HID) + k;
        #pragma unroll
        for (int c = 0; c < 8; ++c) {
            WR[c] = pr[c * 16]; WZ[c] = pz[c * 16]; WN[c] = pn[c * 16];
        }
    }
    // pin: values become opaque -> no remat/sinking into the loop
    #pragma unroll
    for (int c = 0; c < 8; ++c) {
        asm volatile("" : "+v"(WR[c].x), "+v"(WR[c].y), "+v"(WR[c].z), "+v"(WR[c].w));
        asm volatile("" : "+v"(WZ[c].x), "+v"(WZ[c].y), "+v"(WZ[c].z), "+v"(WZ[c].w));
        asm volatile("" : "+v"(WN[c].x), "+v"(WN[c].y), "+v"(WN[c].z), "+v"(WN[c].w));
    }

    // ---- one-time LDS staging ----
    for (int idx = tid; idx < 6 * 96; idx += NTHR) {
        int v = idx / 96, rem = idx - v * 96, gate = rem >> 5, j = rem & 31;
        float val = ws[WS_GX + v * G3H + gate * HID + r * 32 + j];
        if (gate < 2) val += b_hh[gate * HID + r * 32 + j];
        gx_lds[idx] = val;
    }
    if (tid < 32) bhn_lds[tid] = b_hh[2 * HID + r * 32 + tid];
    for (int q = tid; q < S_LEN; q += NTHR) seq_lds[q] = (unsigned char)seq[q];

    // ---- zero-init OWN hbuf words, both parities (kills stale tags from
    // prior graph replays in both the local L2 and the MALL copy) ----
    if (tid < 64) {
        unsigned long long* dst = &hbuf[(tid >> 5) * HID + r * 32 + (tid & 31)];
        unsigned long long zero = 0ull;
        asm volatile("global_store_dwordx2 %0, %1, off sc0\n\t"
                     "global_store_dwordx2 %0, %1, off sc0 sc1"
                     :: "v"(dst), "v"(zero));
    }
    __syncthreads();   // drains vmcnt: zero-init ordered before t-loop stores

    for (int t = 0; t < S_LEN; ++t) {
        const int p = t & 1;
        int v = seq_lds[t];
        float gxr = gx_lds[v * 96 + rowg];
        float gxz = gx_lds[v * 96 + 32 + rowg];
        float gxn = gx_lds[v * 96 + 64 + rowg];

        // poll own tagged word (sc0 fast path, periodic MALL escalation)
        {
            const unsigned long long* src = &hbuf[p * HID + tid];
            unsigned long long w;
            int spin = 0;
            for (;;) {
                if ((++spin & 63) == 0)
                    asm volatile("global_load_dwordx2 %0, %1, off sc0 sc1\n\t"
                                 "s_waitcnt vmcnt(0)"
                                 : "=v"(w) : "v"(src));
                else
                    asm volatile("global_load_dwordx2 %0, %1, off sc0\n\t"
                                 "s_waitcnt vmcnt(0)"
                                 : "=v"(w) : "v"(src));
                if ((unsigned)(w >> 32) == (unsigned)t) break;
            }
            h_lds[p][tid] = __uint_as_float((unsigned)w);
        }
        __syncthreads();   // sole barrier per step (parity double buffer)

        // dot over this lane's columns: chunk c = cols c*64 + k*4 .. +3
        // (a wave's 16 lanes read 256B contiguous -> conflict-free b128 reads)
        float ar = 0.f, az = 0.f, an = 0.f;
        const float4* hp = (const float4*)&h_lds[p][0] + k;
        #pragma unroll
        for (int c = 0; c < 8; ++c) {
            float4 hv = hp[c * 16];
            ar += WR[c].x * hv.x; ar += WR[c].y * hv.y;
            ar += WR[c].z * hv.z; ar += WR[c].w * hv.w;
            az += WZ[c].x * hv.x; az += WZ[c].y * hv.y;
            az += WZ[c].z * hv.z; az += WZ[c].w * hv.w;
            an += WN[c].x * hv.x; an += WN[c].y * hv.y;
            an += WN[c].z * hv.z; an += WN[c].w * hv.w;
        }
        // reduce across the 16 lanes of the column group
        #pragma unroll
        for (int m = 1; m < 16; m <<= 1) {
            ar += __shfl_xor(ar, m, 16);
            az += __shfl_xor(az, m, 16);
            an += __shfl_xor(an, m, 16);
        }

        float rg = __fdividef(1.f, 1.f + __expf(-(gxr + ar)));
        float zg = __fdividef(1.f, 1.f + __expf(-(gxz + az)));
        float nx = gxn + rg * (an + bhn_lds[rowg]);
        float ng = 1.f - __fdividef(2.f, 1.f + __expf(2.f * nx));  // tanh
        float hold = h_lds[p][row];
        float hn = (1.f - zg) * ng + zg * hold;

        if (k == 0) {
            unsigned long long wout =
                ((unsigned long long)(unsigned)(t + 1) << 32) |
                (unsigned long long)__float_as_uint(hn);
            unsigned long long* dst = &hbuf[(1 - p) * HID + row];
            asm volatile("global_store_dwordx2 %0, %1, off sc0\n\t"
                         "global_store_dwordx2 %0, %1, off sc0 sc1"
                         :: "v"(dst), "v"(wout));
        }
        // no trailing barrier: next step stages into h_lds[1-p]
    }

    // ---- epilogue: rank-0 WG computes out = W_out @ h_T + b_out ----
    if (r == 0) {
        // h_{S_LEN} lives in parity 0 with tag S_LEN
        const unsigned long long* src = &hbuf[0 * HID + tid];
        unsigned long long w;
        int spin = 0;
        for (;;) {
            if ((++spin & 63) == 0)
                asm volatile("global_load_dwordx2 %0, %1, off sc0 sc1\n\t"
                             "s_waitcnt vmcnt(0)"
                             : "=v"(w) : "v"(src));
            else
                asm volatile("global_load_dwordx2 %0, %1, off sc0\n\t"
                             "s_waitcnt vmcnt(0)"
                             : "=v"(w) : "v"(src));
            if ((unsigned)(w >> 32) == (unsigned)S_LEN) break;
        }
        h_lds[0][tid] = __uint_as_float((unsigned)w);
        __syncthreads();
        // wave wid computes out[wid] (NOUT == 8 == waves per WG)
        const int wid  = tid >> 6;
        const int lane = tid & 63;
        float s = 0.f;
        #pragma unroll
        for (int m = 0; m < 8; ++m) {
            int j = lane + 64 * m;
            s += W_out[wid * HID + j] * h_lds[0][j];
        }
        #pragma unroll
        for (int m = 1; m < 64; m <<= 1) s += __shfl_xor(s, m, 64);
        if (lane == 0) out[wid] = s + b_out[wid];
    }
}

extern "C" void kernel_launch(void* const* d_in, const int* in_sizes, int n_in,
                              void* d_out, int out_size, void* d_ws, size_t ws_size,
                              hipStream_t stream) {
    const int*   seq   = (const int*)d_in[0];
    const float* emb   = (const float*)d_in[1];
    const float* W_ih  = (const float*)d_in[2];
    const float* W_hh  = (const float*)d_in[3];
    const float* b_ih  = (const float*)d_in[4];
    const float* b_hh  = (const float*)d_in[5];
    const float* W_out = (const float*)d_in[6];
    const float* b_out = (const float*)d_in[7];
    float* ws = (float*)d_ws;
    float* out = (float*)d_out;

    gru_precompute_kernel<<<36, 256, 0, stream>>>(emb, W_ih, b_ih, ws);
    gru_persistent_kernel<<<NBLK, NTHR, 0, stream>>>(seq, W_hh, b_hh, W_out, b_out,
                                                     ws, out);
}

// Round 6
// 88236.206 us; speedup vs baseline: 2.8696x; 2.8696x over previous
//
#include <hip/hip_runtime.h>

#define S_LEN 32768
#define EMB   256
#define HID   512
#define G3H   1536   // 3*HID
#define NWG   64
#define NTHR  512
#define NOUT  8

// ws layout (float units):
// [0, 9216)        gx_table (6 x 1536)  : emb@W_ih.T + b_ih
// [9216, 11264)    hbuf: 2 x 512 tagged u64 words. word = (tag<<32)|f32bits
#define WS_GX    0
#define WS_HBUF  9216

__global__ __launch_bounds__(256) void gru_precompute_kernel(
    const float* __restrict__ emb, const float* __restrict__ W_ih,
    const float* __restrict__ b_ih, float* __restrict__ ws)
{
    int idx = blockIdx.x * 256 + threadIdx.x;
    if (idx < 6 * G3H) {
        int v = idx / G3H, r = idx - v * G3H;
        const float* er = emb + v * EMB;
        const float* wr = W_ih + r * EMB;
        float s = 0.f;
        #pragma unroll 8
        for (int e = 0; e < EMB; ++e) s += er[e] * wr[e];
        ws[WS_GX + idx] = s + b_ih[r];
    }
    if (blockIdx.x == 0) {
        // zero the tagged h buffer (tag 0 == h_0 == 0) with agent-scope stores
        // so the persistent kernel's polls see them (proven in round 3).
        for (int j = threadIdx.x; j < 2048; j += 256)
            __hip_atomic_store((int*)&ws[WS_HBUF + j], 0,
                               __ATOMIC_RELAXED, __HIP_MEMORY_SCOPE_AGENT);
    }
}

// Persistent GRU: 64 WGs x 512 threads. WG r owns h rows [r*8, r*8+8);
// wave w (tid>>6) owns row r*8+w; lane l covers columns {4l..4l+3} and
// {256+4l..256+4l+3} of that row for all 3 gates -> 6 float4 = 24 weight
// VGPRs per lane (trivially register-resident; no allocator fight).
// h exchange: round-3 protocol verbatim — tagged (tag<<32|f32bits) u64,
// __hip_atomic relaxed agent-scope load/store, tag exact-match poll.
__global__ __launch_bounds__(512, 1) void gru_persistent_kernel(
    const int* __restrict__ seq, const float* __restrict__ W_hh,
    const float* __restrict__ b_hh, const float* __restrict__ W_out,
    const float* __restrict__ b_out, float* __restrict__ ws,
    float* __restrict__ out)
{
    const int r   = blockIdx.x;          // 0..63
    const int tid = threadIdx.x;
    const int w   = tid >> 6;            // wave id = local row 0..7
    const int l   = tid & 63;            // lane in wave
    const int row = r * 8 + w;           // global h row

    __shared__ __align__(16) float h_lds[2][HID];
    __shared__ float gx_lds[6 * 24];     // [v][gate][localrow], b_hh folded for r,z
    __shared__ unsigned char seq_lds[S_LEN];

    unsigned long long* hbuf = (unsigned long long*)(ws + WS_HBUF);

    // ---- one-time weight load: 6 named float4 (no arrays -> no scratch risk)
    const float4* W4 = (const float4*)W_hh;     // 128 float4 per 512-col row
    const size_t br = (size_t)(0 * HID + row) * 128;
    const size_t bz = (size_t)(1 * HID + row) * 128;
    const size_t bn = (size_t)(2 * HID + row) * 128;
    float4 WR0 = W4[br + l], WR1 = W4[br + 64 + l];
    float4 WZ0 = W4[bz + l], WZ1 = W4[bz + 64 + l];
    float4 WN0 = W4[bn + l], WN1 = W4[bn + 64 + l];
    const float bhn = b_hh[2 * HID + row];      // n-gate bias, uniform per wave

    // ---- one-time LDS staging ----
    for (int idx = tid; idx < 6 * 24; idx += NTHR) {
        int v = idx / 24, rem = idx - v * 24, gate = rem >> 3, j = rem & 7;
        float val = ws[WS_GX + v * G3H + gate * HID + r * 8 + j];
        if (gate < 2) val += b_hh[gate * HID + r * 8 + j];  // fold b_hh for r,z
        gx_lds[idx] = val;
    }
    for (int q = tid; q < S_LEN; q += NTHR) seq_lds[q] = (unsigned char)seq[q];
    __syncthreads();

    for (int t = 0; t < S_LEN; ++t) {
        const int p = t & 1;
        // h-independent prefetch
        int v = seq_lds[t];
        float gxr = gx_lds[v * 24 + w];
        float gxz = gx_lds[v * 24 + 8 + w];
        float gxn = gx_lds[v * 24 + 16 + w];

        // poll own tagged word (single fused round trip), stage into LDS
        unsigned long long hw;
        do {
            hw = __hip_atomic_load(&hbuf[p * HID + tid], __ATOMIC_RELAXED,
                                   __HIP_MEMORY_SCOPE_AGENT);
        } while ((unsigned)(hw >> 32) != (unsigned)t);
        h_lds[p][tid] = __uint_as_float((unsigned)hw);
        __syncthreads();   // sole barrier per step (parity double buffer)

        // dot over this lane's 8 columns (2 float4), 3 gates
        const float4* h4 = (const float4*)&h_lds[p][0];
        float4 h0 = h4[l], h1 = h4[64 + l];
        float ar = WR0.x * h0.x + WR0.y * h0.y + WR0.z * h0.z + WR0.w * h0.w
                 + WR1.x * h1.x + WR1.y * h1.y + WR1.z * h1.z + WR1.w * h1.w;
        float az = WZ0.x * h0.x + WZ0.y * h0.y + WZ0.z * h0.z + WZ0.w * h0.w
                 + WZ1.x * h1.x + WZ1.y * h1.y + WZ1.z * h1.z + WZ1.w * h1.w;
        float an = WN0.x * h0.x + WN0.y * h0.y + WN0.z * h0.z + WN0.w * h0.w
                 + WN1.x * h1.x + WN1.y * h1.y + WN1.z * h1.z + WN1.w * h1.w;

        // full-wave butterfly reduce (row dot complete in every lane)
        #pragma unroll
        for (int m = 1; m < 64; m <<= 1) {
            ar += __shfl_xor(ar, m, 64);
            az += __shfl_xor(az, m, 64);
            an += __shfl_xor(an, m, 64);
        }

        float rg = __fdividef(1.f, 1.f + __expf(-(gxr + ar)));
        float zg = __fdividef(1.f, 1.f + __expf(-(gxz + az)));
        float nx = gxn + rg * (an + bhn);
        float ng = 1.f - __fdividef(2.f, 1.f + __expf(2.f * nx));  // tanh
        float hold = h_lds[p][row];         // broadcast read
        float hn = (1.f - zg) * ng + zg * hold;

        if (l == 0) {
            unsigned long long wo =
                ((unsigned long long)(unsigned)(t + 1) << 32) |
                (unsigned long long)__float_as_uint(hn);
            __hip_atomic_store(&hbuf[(1 - p) * HID + row], wo,
                               __ATOMIC_RELAXED, __HIP_MEMORY_SCOPE_AGENT);
        }
        // no trailing barrier: next step stages into h_lds[1-p]
    }

    // ---- epilogue: WG 0 computes out = W_out @ h_T + b_out ----
    if (r == 0) {
        // h_{S_LEN} lives in parity 0 with tag S_LEN
        unsigned long long hw;
        do {
            hw = __hip_atomic_load(&hbuf[0 * HID + tid], __ATOMIC_RELAXED,
                                   __HIP_MEMORY_SCOPE_AGENT);
        } while ((unsigned)(hw >> 32) != (unsigned)S_LEN);
        h_lds[0][tid] = __uint_as_float((unsigned)hw);
        __syncthreads();
        // wave w computes out[w] (NOUT == 8 == waves per WG)
        float s = 0.f;
        #pragma unroll
        for (int m = 0; m < 8; ++m) {
            int j = l + 64 * m;
            s += W_out[w * HID + j] * h_lds[0][j];
        }
        #pragma unroll
        for (int m = 1; m < 64; m <<= 1) s += __shfl_xor(s, m, 64);
        if (l == 0) out[w] = s + b_out[w];
    }
}

extern "C" void kernel_launch(void* const* d_in, const int* in_sizes, int n_in,
                              void* d_out, int out_size, void* d_ws, size_t ws_size,
                              hipStream_t stream) {
    const int*   seq   = (const int*)d_in[0];
    const float* emb   = (const float*)d_in[1];
    const float* W_ih  = (const float*)d_in[2];
    const float* W_hh  = (const float*)d_in[3];
    const float* b_ih  = (const float*)d_in[4];
    const float* b_hh  = (const float*)d_in[5];
    const float* W_out = (const float*)d_in[6];
    const float* b_out = (const float*)d_in[7];
    float* ws = (float*)d_ws;
    float* out = (float*)d_out;

    gru_precompute_kernel<<<36, 256, 0, stream>>>(emb, W_ih, b_ih, ws);
    gru_persistent_kernel<<<NWG, NTHR, 0, stream>>>(seq, W_hh, b_hh, W_out, b_out,
                                                    ws, out);
}